// Round 5
// baseline (563.416 us; speedup 1.0000x reference)
//
#include <hip/hip_runtime.h>
#include <math.h>

#define B_ 8
#define N_ 1024
#define M_ 20000
#define C_ 80
#define G_ 64
typedef unsigned long long ull;

// ws layout: gtiou [B][64][64] f32 (128 KB) | elem [B][1024][2] float4 (256 KB)
//            | adj [B][1024][64] u16 (1 MB)  -- total 1.375 MB
#define WS_GTIOU_OFF 0
#define WS_ELEM_OFF  (131072)
#define WS_ADJ_OFF   (131072 + 262144)

__device__ __forceinline__ float iou1(float ax, float ay, float az, float aw,
                                      float bx, float by, float bz, float bw) {
    // legacy +1 convention, exact reference arithmetic order
    float lx = fmaxf(ax, bx), ly = fmaxf(ay, by);
    float rx = fminf(az, bz), ry = fminf(aw, bw);
    float w = fmaxf(rx - lx + 1.0f, 0.0f), h = fmaxf(ry - ly + 1.0f, 0.0f);
    float ov = w * h;
    float a1 = (az - ax + 1.0f) * (aw - ay + 1.0f);
    float a2 = (bx > bz) ? 0.f : (bz - bx + 1.0f) * (bw - by + 1.0f);  // bx>bz never true here
    return ov / (a1 + a2 - ov);
}

// ---- Kernel 1: scores, bitonic sort (1024 thr), gt-gt IoU, sorted element table ----
__global__ __launch_bounds__(1024) void prep_kernel(
    const int* __restrict__ pos_inds, const int* __restrict__ pos_gt,
    const float* __restrict__ gt_bboxes, const float* __restrict__ bbox_preds,
    const float* __restrict__ cls_scores, const int* __restrict__ gt_labels,
    float* __restrict__ gtiouG, float4* __restrict__ elemG) {
    const int b = blockIdx.x, t = threadIdx.x;
    __shared__ ull s_keys[N_];

    {
        int g = pos_gt[b * N_ + t];
        int lab = gt_labels[b * G_ + g];
        int pi = pos_inds[b * N_ + t];
        float s = cls_scores[(size_t)b * (M_ * C_) + (size_t)pi * C_ + lab];
        // descending score, tie -> ascending original index (jnp.argmax tie-break)
        s_keys[t] = ((ull)(~__float_as_uint(s)) << 32) | (unsigned)t;
    }
    __syncthreads();

    for (int k = 2; k <= N_; k <<= 1) {
        for (int jj = k >> 1; jj; jj >>= 1) {
            if ((t & jj) == 0) {
                int pr = t | jj;
                ull a = s_keys[t], c = s_keys[pr];
                bool up = ((t & k) == 0);
                if ((a > c) == up) { s_keys[t] = c; s_keys[pr] = a; }
            }
            __syncthreads();
        }
    }

    const float* gb = gt_bboxes + (size_t)b * G_ * 4;
    for (int e = t; e < G_ * G_; e += 1024) {
        int r = e >> 6, c = e & 63;
        gtiouG[(size_t)b * 4096 + e] =
            iou1(gb[r * 4], gb[r * 4 + 1], gb[r * 4 + 2], gb[r * 4 + 3],
                 gb[c * 4], gb[c * 4 + 1], gb[c * 4 + 2], gb[c * 4 + 3]);
    }

    {
        ull key = s_keys[t];
        int j = (int)(unsigned)(key & 0xFFFFFFFFull);
        float s = __uint_as_float(~(unsigned)(key >> 32));   // exact score recovery
        const float* bp = bbox_preds + (size_t)(b * N_ + j) * 4;
        float x0 = bp[0], y0 = bp[1], x1 = bp[2], y1 = bp[3];
        int g = pos_gt[b * N_ + j];
        float area = (x1 - x0 + 1.0f) * (y1 - y0 + 1.0f);
        elemG[(size_t)(b * N_ + t) * 2 + 0] = make_float4(x0, y0, x1, y1);
        elemG[(size_t)(b * N_ + t) * 2 + 1] = make_float4(__int_as_float(g), s, area, 0.f);
    }
}

// ---- Kernel 2: adjacency bits in sorted space: bit = (iou > 0.5), i.e. 3I > a1+a2 ----
__global__ __launch_bounds__(256) void adj_kernel(
    const float4* __restrict__ elemG, unsigned short* __restrict__ adjG) {
    const int b = blockIdx.y;
    const int r = blockIdx.x * 4 + (threadIdx.x >> 6);
    const int lane = threadIdx.x & 63;
    float4 rA = elemG[(size_t)(b * N_ + r) * 2];
    float ax0 = rA.x, ay0 = rA.y;
    float az1 = rA.z + 1.0f, aw1 = rA.w + 1.0f;
    float a1 = (rA.z - rA.x + 1.0f) * (rA.w - rA.y + 1.0f);
    unsigned bits = 0;
#pragma unroll
    for (int u = 0; u < 16; ++u) {
        int cpos = lane * 16 + u;
        float4 cA = elemG[(size_t)(b * N_ + cpos) * 2];
        float lx = fmaxf(ax0, cA.x), ly = fmaxf(ay0, cA.y);
        float rx = fminf(az1, cA.z + 1.0f), ry = fminf(aw1, cA.w + 1.0f);
        float w = fmaxf(rx - lx, 0.0f), h = fmaxf(ry - ly, 0.0f);
        float I = w * h;
        float a2 = (cA.z - cA.x + 1.0f) * (cA.w - cA.y + 1.0f);
        bits |= (3.0f * I > a1 + a2) ? (1u << u) : 0u;
    }
    adjG[(size_t)(b * N_ + r) * 64 + lane] = (unsigned short)bits;
}

// ---- Kernel 3: sequential loop; speculative next-pop prefetch; SALU seen-mask ----
__global__ __launch_bounds__(64) void nms_seq_kernel(
    const float4* __restrict__ elemG, const unsigned short* __restrict__ adjG,
    const float* __restrict__ gtiouG, float* __restrict__ out) {
    const int b = blockIdx.x, lane = threadIdx.x;
    __shared__ float4 s_elem4[N_ * 2];          // 32 KB: popped-element broadcast
    __shared__ unsigned short s_adj[128 * 64];  // 16 KB: 128-row rolling window

    // per-lane register copies (rare phase-2 only); also populate s_elem4
    float bx0[16], by0[16], bz1[16], bw1[16], a2[16], sc[16];
    int gti[16];
#pragma unroll
    for (int u = 0; u < 16; ++u) {
        int p = lane * 16 + u;
        float4 eA = elemG[(size_t)(b * N_ + p) * 2];
        float4 eB = elemG[(size_t)(b * N_ + p) * 2 + 1];
        bx0[u] = eA.x; by0[u] = eA.y; bz1[u] = eA.z + 1.0f; bw1[u] = eA.w + 1.0f;
        a2[u] = eB.z; sc[u] = eB.y; gti[u] = __float_as_int(eB.x);
        s_elem4[p * 2] = eA; s_elem4[p * 2 + 1] = eB;
    }
    {   // preload adjacency rows 0..127
        const uint4* asrc = (const uint4*)(adjG + (size_t)b * N_ * 64);
        uint4* adst = (uint4*)s_adj;
        for (int c = 0; c < 16; ++c) adst[c * 64 + lane] = asrc[c * 64 + lane];
    }
    __syncthreads();

    unsigned mask = 0xFFFFu;   // bit u = position lane*16+u alive (lane-major)
    ull seen_mask = 0ull;      // wave-uniform: bit g = gt g has a first-seen box (SALU test)
    float sx0 = 0.f, sy0 = 0.f, sx1 = 0.f, sy1 = 0.f;   // lane g: first-seen box of gt g
    float tpull = 0.f, tpush = 0.f;
    int pcnt = 0, qcnt = 0;
    int loaded_hi = 128;
    const float* gt_b = gtiouG + (size_t)b * 4096;

    int p = 0;   // current pop = first alive sorted position; strictly increasing
    float4 eA = s_elem4[0], eB = s_elem4[1];
    unsigned row = s_adj[lane];

    while (true) {
        const int g = __builtin_amdgcn_readfirstlane(__float_as_int(eB.x));
        const float score_i = eB.y, a1 = eB.z;
        const float ix0 = eA.x, iy0 = eA.y, ix1 = eA.z, iy1 = eA.w;

        // seen-state BEFORE update; pcnt/seen NOT gated on remaining (reference order)
        const bool hs = (seen_mask >> g) & 1ull;
        pcnt += hs ? 1 : 0;
        if (!hs) {
            seen_mask |= (1ull << g);
            if (lane == g) { sx0 = ix0; sy0 = iy0; sx1 = ix1; sy1 = iy1; }
        }

        // remove popped, then 'remaining' (reference order: pre-kill)
        if (lane == (p >> 4)) mask &= ~(1u << (p & 15));
        ull bal0 = __ballot(mask != 0u);
        if (bal0 == 0ull) break;   // drop this step's pull/push

        // speculative next pop (ignores this step's kills) + prefetch its data
        int sl = __ffsll(bal0) - 1;
        unsigned sml = (unsigned)__builtin_amdgcn_readlane((int)mask, sl);
        int sp = sl * 16 + (__ffs((int)sml) - 1);
        float4 nA = s_elem4[sp * 2];
        float4 nB = s_elem4[sp * 2 + 1];
        unsigned nrow = s_adj[((sp & 127) << 6) + lane];   // garbage if sp >= loaded_hi (handled)

        // kill: state-independent adjacency bits & alive
        unsigned kill = row & mask;
        mask &= ~kill;

        // pull accumulate (remaining true here)
        if (hs) {
            float px0 = __int_as_float(__builtin_amdgcn_readlane(__float_as_int(sx0), g));
            float py0 = __int_as_float(__builtin_amdgcn_readlane(__float_as_int(sy0), g));
            float px1 = __int_as_float(__builtin_amdgcn_readlane(__float_as_int(sx1), g));
            float py1 = __int_as_float(__builtin_amdgcn_readlane(__float_as_int(sy1), g));
            float ovpi = iou1(px0, py0, px1, py1, ix0, iy0, ix1, iy1);
            tpull += -__logf(0.5f + fmaxf(ovpi, 1e-6f)) * score_i;
        }

        // rare push terms (exact IoU recompute for killed elements of other gts)
        if (__ballot(kill != 0u) != 0ull) {
            int cnt = 0; float ts = 0.f;
            float az1 = ix1 + 1.0f, aw1 = iy1 + 1.0f;
#pragma unroll
            for (int u = 0; u < 16; ++u) {
                if ((kill >> u) & 1u) {
                    int gj = gti[u];
                    if (gj != g) {
                        float lx = fmaxf(ix0, bx0[u]), ly = fmaxf(iy0, by0[u]);
                        float rx = fminf(az1, bz1[u]), ry = fminf(aw1, bw1[u]);
                        float w = fmaxf(rx - lx, 0.0f), h = fmaxf(ry - ly, 0.0f);
                        float I = w * h;
                        float ov = I / (a1 + a2[u] - I);
                        if (ov > gt_b[g * 64 + gj]) { cnt += 1; ts -= __logf(1.0f - ov) * sc[u]; }
                    }
                }
            }
#pragma unroll
            for (int off = 32; off; off >>= 1) {
                cnt += __shfl_xor(cnt, off);
                ts += __shfl_xor(ts, off);
            }
            if (cnt > 0) { tpush += ts / (float)cnt; qcnt += cnt; }
        }

        // true next pop; spec-hit keeps prefetched data (LDS latency already hidden)
        ull bal1 = __ballot(mask != 0u);
        if (bal1 == 0ull) break;
        int l2 = __ffsll(bal1) - 1;
        unsigned ml2 = (unsigned)__builtin_amdgcn_readlane((int)mask, l2);
        int np = l2 * 16 + (__ffs((int)ml2) - 1);
        bool hit = (np == sp) && (sp < loaded_hi);
        p = np;
        if (!hit && np != sp) {   // wrong element speculated: re-read its table entry
            nA = s_elem4[np * 2];
            nB = s_elem4[np * 2 + 1];
        }
        // window refill: keep 64-row lookahead; overwritten rows are < p (monotone) => dead
        while (loaded_hi < N_ && p + 64 > loaded_hi) {
            const uint4* rs = (const uint4*)(adjG + (size_t)b * N_ * 64 + (size_t)loaded_hi * 64);
            uint4* rd = (uint4*)(s_adj + ((loaded_hi & 127) << 6));
            for (int c = 0; c < 8; ++c) rd[c * 64 + lane] = rs[c * 64 + lane];
            loaded_hi += 64;
        }
        if (!hit) nrow = s_adj[((p & 127) << 6) + lane];   // row now guaranteed in window
        eA = nA; eB = nB; row = nrow;
    }

    if (lane == 0) {
        atomicAdd(&out[0], (tpush / ((float)qcnt + 1e-6f)) * 0.125f);  // mean push, B=8
        atomicAdd(&out[1], (tpull / ((float)pcnt + 1e-6f)) * 0.125f);  // mean pull
    }
}

extern "C" void kernel_launch(void* const* d_in, const int* in_sizes, int n_in,
                              void* d_out, int out_size, void* d_ws, size_t ws_size,
                              hipStream_t stream) {
    const int* pos_inds = (const int*)d_in[0];
    const int* pos_gt = (const int*)d_in[1];
    const float* gt_bboxes = (const float*)d_in[2];
    const float* bbox_preds = (const float*)d_in[3];
    const float* cls_scores = (const float*)d_in[4];
    const int* gt_labels = (const int*)d_in[5];
    float* out = (float*)d_out;

    float* gtiouG = (float*)((char*)d_ws + WS_GTIOU_OFF);
    float4* elemG = (float4*)((char*)d_ws + WS_ELEM_OFF);
    unsigned short* adjG = (unsigned short*)((char*)d_ws + WS_ADJ_OFF);

    hipMemsetAsync(out, 0, 2 * sizeof(float), stream);  // d_out re-poisoned 0xAA each call
    prep_kernel<<<dim3(B_), dim3(1024), 0, stream>>>(
        pos_inds, pos_gt, gt_bboxes, bbox_preds, cls_scores, gt_labels, gtiouG, elemG);
    adj_kernel<<<dim3(256, B_), dim3(256), 0, stream>>>(elemG, adjG);
    nms_seq_kernel<<<dim3(B_), dim3(64), 0, stream>>>(elemG, adjG, gtiouG, out);
}

// Round 6
// 245.417 us; speedup vs baseline: 2.2957x; 2.2957x over previous
//
#include <hip/hip_runtime.h>
#include <math.h>

#define B_ 8
#define N_ 1024
#define M_ 20000
#define C_ 80
#define G_ 64
typedef unsigned long long ull;

// ws: elem [B][1024][2]float4 (256KB) | adj [B][1024][64]u16 (1MB)
//     | surv [B][1024]int (32KB) | K [B]int   -- total ~1.31MB (< R4's 1.375MB)
#define WS_ELEM_OFF 0
#define WS_ADJ_OFF  262144
#define WS_SURV_OFF 1310720
#define WS_K_OFF    1343488

__device__ __forceinline__ float iou1(float ax, float ay, float az, float aw,
                                      float bx, float by, float bz, float bw) {
    // legacy +1 convention, exact reference arithmetic order
    float lx = fmaxf(ax, bx), ly = fmaxf(ay, by);
    float rx = fminf(az, bz), ry = fminf(aw, bw);
    float w = fmaxf(rx - lx + 1.0f, 0.0f), h = fmaxf(ry - ly + 1.0f, 0.0f);
    float ov = w * h;
    float a1 = (az - ax + 1.0f) * (aw - ay + 1.0f);
    float a2 = (bz - bx + 1.0f) * (bw - by + 1.0f);
    return ov / (a1 + a2 - ov);
}

// ---- K1: scores + register-resident bitonic sort (shfl intra-wave) + element table ----
__global__ __launch_bounds__(1024) void prep_kernel(
    const int* __restrict__ pos_inds, const int* __restrict__ pos_gt,
    const float* __restrict__ bbox_preds, const float* __restrict__ cls_scores,
    const int* __restrict__ gt_labels, float4* __restrict__ elemG) {
    const int b = blockIdx.x, t = threadIdx.x;
    __shared__ ull s_keys[N_];

    int g0 = pos_gt[b * N_ + t];
    int lab = gt_labels[b * G_ + g0];
    int pi = pos_inds[b * N_ + t];
    float s = cls_scores[(size_t)b * (M_ * C_) + (size_t)pi * C_ + lab];
    // descending score, tie -> ascending original index (jnp.argmax tie-break)
    ull key = ((ull)(~__float_as_uint(s)) << 32) | (unsigned)t;

    for (unsigned k2 = 2; k2 <= N_; k2 <<= 1) {
        for (unsigned jj = k2 >> 1; jj; jj >>= 1) {
            ull other;
            if (jj >= 64) {   // cross-wave: LDS exchange (only 10 such passes)
                s_keys[t] = key; __syncthreads();
                other = s_keys[t ^ jj]; __syncthreads();
            } else {          // intra-wave: register shfl, no barrier
                int lo = __shfl_xor((int)(unsigned)key, (int)jj);
                int hi = __shfl_xor((int)(unsigned)(key >> 32), (int)jj);
                other = ((ull)(unsigned)hi << 32) | (unsigned)lo;
            }
            bool keep_min = (((t & jj) == 0) == ((t & k2) == 0));
            ull mn = key < other ? key : other;
            ull mx = key < other ? other : key;
            key = keep_min ? mn : mx;
        }
    }

    int j = (int)(unsigned)(key & 0xFFFFFFFFull);
    float ss = __uint_as_float(~(unsigned)(key >> 32));   // exact score recovery
    const float* bp = bbox_preds + (size_t)(b * N_ + j) * 4;
    float x0 = bp[0], y0 = bp[1], x1 = bp[2], y1 = bp[3];
    int g = pos_gt[b * N_ + j];
    float area = (x1 - x0 + 1.0f) * (y1 - y0 + 1.0f);
    elemG[(size_t)(b * N_ + t) * 2 + 0] = make_float4(x0, y0, x1, y1);
    elemG[(size_t)(b * N_ + t) * 2 + 1] = make_float4(__int_as_float(g), ss, area, 0.f);
}

// ---- K2: adjacency bits in sorted space: bit q of row r = (iou(r,q) > 0.5) ----
// row layout: u16[64], word w bit u = position w*16+u  == linear 1024-bit mask
__global__ __launch_bounds__(256) void adj_kernel(
    const float4* __restrict__ elemG, unsigned short* __restrict__ adjG) {
    const int b = blockIdx.y;
    const int r = blockIdx.x * 4 + (threadIdx.x >> 6);
    const int lane = threadIdx.x & 63;
    float4 rA = elemG[(size_t)(b * N_ + r) * 2];
    float ax0 = rA.x, ay0 = rA.y;
    float az1 = rA.z + 1.0f, aw1 = rA.w + 1.0f;
    float a1 = (rA.z - rA.x + 1.0f) * (rA.w - rA.y + 1.0f);
    unsigned bits = 0;
#pragma unroll
    for (int u = 0; u < 16; ++u) {
        int cpos = lane * 16 + u;
        float4 cA = elemG[(size_t)(b * N_ + cpos) * 2];
        float lx = fmaxf(ax0, cA.x), ly = fmaxf(ay0, cA.y);
        float rx = fminf(az1, cA.z + 1.0f), ry = fminf(aw1, cA.w + 1.0f);
        float w = fmaxf(rx - lx, 0.0f), h = fmaxf(ry - ly, 0.0f);
        float I = w * h;
        float a2 = (cA.z - cA.x + 1.0f) * (cA.w - cA.y + 1.0f);
        bits |= (3.0f * I > a1 + a2) ? (1u << u) : 0u;   // iou>0.5 <=> 3I > a1+a2
    }
    adjG[(size_t)(b * N_ + r) * 64 + lane] = (unsigned short)bits;
}

// ---- K3: minimal sequential sweep: survivors only (mask &= ~row; next = ffs) ----
__global__ __launch_bounds__(64) void sweep_kernel(
    const unsigned short* __restrict__ adjG, int* __restrict__ survG,
    int* __restrict__ KG) {
    const int b = blockIdx.x, lane = threadIdx.x;
    __shared__ unsigned short s_adj[128 * 64];   // 16KB rolling window
    {
        const uint4* asrc = (const uint4*)(adjG + (size_t)b * N_ * 64);
        uint4* adst = (uint4*)s_adj;
        for (int c = 0; c < 16; ++c) adst[c * 64 + lane] = asrc[c * 64 + lane];
    }
    __syncthreads();

    unsigned mask = 0xFFFFu;   // bit u = position lane*16+u alive
    int loaded_hi = 128;
    int p = 0, k = 0;          // pops strictly monotone in sorted position
    int* surv = survG + b * N_;
    while (true) {
        if (lane == 0) surv[k] = p;   // off critical path (store queue)
        k++;
        unsigned row = s_adj[((p & 127) << 6) + lane];
        mask &= ~row;                 // kills neighbors AND self (adj(p,p)=1)
        ull bal = __ballot(mask != 0u);
        if (bal == 0ull) break;
        int l = __ffsll(bal) - 1;
        unsigned ml = (unsigned)__builtin_amdgcn_readlane((int)mask, l);
        p = l * 16 + (__ffs((int)ml) - 1);
        while (loaded_hi < N_ && p + 64 > loaded_hi) {   // overwritten rows < p => dead
            const uint4* rs = (const uint4*)(adjG + (size_t)b * N_ * 64 + (size_t)loaded_hi * 64);
            uint4* rd = (uint4*)(s_adj + ((loaded_hi & 127) << 6));
            for (int c = 0; c < 8; ++c) rd[c * 64 + lane] = rs[c * 64 + lane];
            loaded_hi += 64;
        }
    }
    if (lane == 0) KG[b] = k;
}

// ---- K4: fully parallel loss from survivor list ----
__global__ __launch_bounds__(256) void loss_kernel(
    const float4* __restrict__ elemG, const unsigned short* __restrict__ adjG,
    const float* __restrict__ gt_bboxes, const int* __restrict__ survG,
    const int* __restrict__ KG, float* __restrict__ out) {
    const int b = blockIdx.x, t = threadIdx.x;
    __shared__ ull s_bits[16];               // survivor bitmask over sorted positions
    __shared__ unsigned short s_step[N_];    // position -> step (0xffff = suppressed)
    __shared__ float s_ts[N_];
    __shared__ int s_cnt[N_], s_kills[N_], s_first[G_];
    __shared__ float s_tpull, s_tpush;
    __shared__ int s_pcnt, s_qcnt;

    const int K = KG[b];
    const int* surv = survG + b * N_;
    for (int i = t; i < N_; i += 256) { s_step[i] = 0xffff; s_ts[i] = 0.f; s_cnt[i] = 0; s_kills[i] = 0; }
    if (t < 16) s_bits[t] = 0ull;
    if (t < G_) s_first[t] = 0x7fffffff;
    if (t == 0) { s_tpull = 0.f; s_tpush = 0.f; s_pcnt = 0; s_qcnt = 0; }
    __syncthreads();

    for (int k = t; k < K; k += 256) {
        int pos = surv[k];
        s_step[pos] = (unsigned short)k;
        atomicOr(&s_bits[pos >> 6], 1ull << (pos & 63));
        float4 eB = elemG[(size_t)(b * N_ + pos) * 2 + 1];
        atomicMin(&s_first[__float_as_int(eB.x)], k);   // first survivor of each gt
    }
    __syncthreads();

    // suppressed j: killer = first survivor q<j with adj(q,j) (symmetry: j's own row)
    for (int j = t; j < N_; j += 256) {
        if (s_step[j] != 0xffff) continue;
        const ull* rowp = (const ull*)(adjG + (size_t)(b * N_ + j) * 64);
        int kp = -1, wtop = j >> 6;
        for (int w = 0; w <= wtop; ++w) {
            ull m = rowp[w] & s_bits[w];
            if (w == wtop) m &= (j & 63) ? ((1ull << (j & 63)) - 1ull) : 0ull;
            if (m) { kp = w * 64 + (int)(__ffsll(m) - 1); break; }
        }
        if (kp < 0) continue;   // unreachable: every non-survivor has a killer
        int q = s_step[kp];
        atomicAdd(&s_kills[q], 1);   // 'remaining' evidence, pre-filter
        float4 qa = elemG[(size_t)(b * N_ + kp) * 2], qb = elemG[(size_t)(b * N_ + kp) * 2 + 1];
        float4 ja = elemG[(size_t)(b * N_ + j) * 2],  jb = elemG[(size_t)(b * N_ + j) * 2 + 1];
        int gq = __float_as_int(qb.x), gj = __float_as_int(jb.x);
        if (gq != gj) {
            float ov = iou1(qa.x, qa.y, qa.z, qa.w, ja.x, ja.y, ja.z, ja.w);
            const float* gbq = gt_bboxes + (size_t)(b * G_ + gq) * 4;
            const float* gbj = gt_bboxes + (size_t)(b * G_ + gj) * 4;
            float gov = iou1(gbq[0], gbq[1], gbq[2], gbq[3], gbj[0], gbj[1], gbj[2], gbj[3]);
            if (ov > gov) {
                atomicAdd(&s_cnt[q], 1);
                atomicAdd(&s_ts[q], -__logf(1.0f - ov) * jb.y);
            }
        }
    }
    __syncthreads();

    // pull per survivor + per-step push normalization
    for (int k = t; k < K; k += 256) {
        int pos = surv[k];
        float4 kB = elemG[(size_t)(b * N_ + pos) * 2 + 1];
        int g = __float_as_int(kB.x);
        int f = s_first[g];
        if (f < k) {
            atomicAdd(&s_pcnt, 1);   // NOT gated on remaining (matches reference)
            // step k's pull dropped iff it is the last pop and kills nobody (remaining=false)
            bool drop = (k == K - 1) && (s_kills[k] == 0);
            if (!drop) {
                int fpos = surv[f];
                float4 fA = elemG[(size_t)(b * N_ + fpos) * 2];
                float4 kA = elemG[(size_t)(b * N_ + pos) * 2];
                float ov = iou1(fA.x, fA.y, fA.z, fA.w, kA.x, kA.y, kA.z, kA.w);
                atomicAdd(&s_tpull, -__logf(0.5f + fmaxf(ov, 1e-6f)) * kB.y);
            }
        }
        if (s_cnt[k] > 0) {   // kills>0 => remaining true => always counted
            atomicAdd(&s_tpush, s_ts[k] / (float)s_cnt[k]);
            atomicAdd(&s_qcnt, s_cnt[k]);
        }
    }
    __syncthreads();
    if (t == 0) {
        atomicAdd(&out[0], (s_tpush / ((float)s_qcnt + 1e-6f)) * 0.125f);  // mean push, B=8
        atomicAdd(&out[1], (s_tpull / ((float)s_pcnt + 1e-6f)) * 0.125f);  // mean pull
    }
}

extern "C" void kernel_launch(void* const* d_in, const int* in_sizes, int n_in,
                              void* d_out, int out_size, void* d_ws, size_t ws_size,
                              hipStream_t stream) {
    const int* pos_inds = (const int*)d_in[0];
    const int* pos_gt = (const int*)d_in[1];
    const float* gt_bboxes = (const float*)d_in[2];
    const float* bbox_preds = (const float*)d_in[3];
    const float* cls_scores = (const float*)d_in[4];
    const int* gt_labels = (const int*)d_in[5];
    float* out = (float*)d_out;

    float4* elemG = (float4*)((char*)d_ws + WS_ELEM_OFF);
    unsigned short* adjG = (unsigned short*)((char*)d_ws + WS_ADJ_OFF);
    int* survG = (int*)((char*)d_ws + WS_SURV_OFF);
    int* KG = (int*)((char*)d_ws + WS_K_OFF);

    hipMemsetAsync(out, 0, 2 * sizeof(float), stream);  // d_out re-poisoned 0xAA each call
    prep_kernel<<<dim3(B_), dim3(1024), 0, stream>>>(
        pos_inds, pos_gt, bbox_preds, cls_scores, gt_labels, elemG);
    adj_kernel<<<dim3(256, B_), dim3(256), 0, stream>>>(elemG, adjG);
    sweep_kernel<<<dim3(B_), dim3(64), 0, stream>>>(adjG, survG, KG);
    loss_kernel<<<dim3(B_), dim3(256), 0, stream>>>(elemG, adjG, gt_bboxes, survG, KG, out);
}

// Round 8
// 210.587 us; speedup vs baseline: 2.6755x; 1.1654x over previous
//
#include <hip/hip_runtime.h>
#include <math.h>

#define B_ 8
#define N_ 1024
#define M_ 20000
#define C_ 80
#define G_ 64
typedef unsigned long long ull;

// ws: elem [B][1024][2]float4 (256KB) | adj [B][1024][64]u16 (1MB)
//     | surv [B][1024]int (32KB) | K [B]int
#define WS_ELEM_OFF 0
#define WS_ADJ_OFF  262144
#define WS_SURV_OFF 1310720
#define WS_K_OFF    1343488

__device__ __forceinline__ float iou1(float ax, float ay, float az, float aw,
                                      float bx, float by, float bz, float bw) {
    // legacy +1 convention, exact reference arithmetic order
    float lx = fmaxf(ax, bx), ly = fmaxf(ay, by);
    float rx = fminf(az, bz), ry = fminf(aw, bw);
    float w = fmaxf(rx - lx + 1.0f, 0.0f), h = fmaxf(ry - ly + 1.0f, 0.0f);
    float ov = w * h;
    float a1 = (az - ax + 1.0f) * (aw - ay + 1.0f);
    float a2 = (bz - bx + 1.0f) * (bw - by + 1.0f);
    return ov / (a1 + a2 - ov);
}

// ---- K1 (R6 verbatim): scores + hybrid bitonic sort + sorted element table ----
__global__ __launch_bounds__(1024) void prep_kernel(
    const int* __restrict__ pos_inds, const int* __restrict__ pos_gt,
    const float* __restrict__ bbox_preds, const float* __restrict__ cls_scores,
    const int* __restrict__ gt_labels, float4* __restrict__ elemG) {
    const int b = blockIdx.x, t = threadIdx.x;
    __shared__ ull s_keys[N_];

    int g0 = pos_gt[b * N_ + t];
    int lab = gt_labels[b * G_ + g0];
    int pi = pos_inds[b * N_ + t];
    float s = cls_scores[(size_t)b * (M_ * C_) + (size_t)pi * C_ + lab];
    // descending score, tie -> ascending original index (jnp.argmax tie-break)
    ull key = ((ull)(~__float_as_uint(s)) << 32) | (unsigned)t;

    for (unsigned k2 = 2; k2 <= N_; k2 <<= 1) {
        for (unsigned jj = k2 >> 1; jj; jj >>= 1) {
            ull other;
            if (jj >= 64) {
                s_keys[t] = key; __syncthreads();
                other = s_keys[t ^ jj]; __syncthreads();
            } else {
                int lo = __shfl_xor((int)(unsigned)key, (int)jj);
                int hi = __shfl_xor((int)(unsigned)(key >> 32), (int)jj);
                other = ((ull)(unsigned)hi << 32) | (unsigned)lo;
            }
            bool keep_min = (((t & jj) == 0) == ((t & k2) == 0));
            ull mn = key < other ? key : other;
            ull mx = key < other ? other : key;
            key = keep_min ? mn : mx;
        }
    }

    int j = (int)(unsigned)(key & 0xFFFFFFFFull);
    float ss = __uint_as_float(~(unsigned)(key >> 32));   // exact score recovery
    const float* bp = bbox_preds + (size_t)(b * N_ + j) * 4;
    float x0 = bp[0], y0 = bp[1], x1 = bp[2], y1 = bp[3];
    int g = pos_gt[b * N_ + j];
    float area = (x1 - x0 + 1.0f) * (y1 - y0 + 1.0f);
    elemG[(size_t)(b * N_ + t) * 2 + 0] = make_float4(x0, y0, x1, y1);
    elemG[(size_t)(b * N_ + t) * 2 + 1] = make_float4(__int_as_float(g), ss, area, 0.f);
}

// ---- K2 (R6 verbatim): adjacency bits: bit q of row r = (iou(r,q) > 0.5) ----
__global__ __launch_bounds__(256) void adj_kernel(
    const float4* __restrict__ elemG, unsigned short* __restrict__ adjG) {
    const int b = blockIdx.y;
    const int r = blockIdx.x * 4 + (threadIdx.x >> 6);
    const int lane = threadIdx.x & 63;
    float4 rA = elemG[(size_t)(b * N_ + r) * 2];
    float ax0 = rA.x, ay0 = rA.y;
    float az1 = rA.z + 1.0f, aw1 = rA.w + 1.0f;
    float a1 = (rA.z - rA.x + 1.0f) * (rA.w - rA.y + 1.0f);
    unsigned bits = 0;
#pragma unroll
    for (int u = 0; u < 16; ++u) {
        int cpos = lane * 16 + u;
        float4 cA = elemG[(size_t)(b * N_ + cpos) * 2];
        float lx = fmaxf(ax0, cA.x), ly = fmaxf(ay0, cA.y);
        float rx = fminf(az1, cA.z + 1.0f), ry = fminf(aw1, cA.w + 1.0f);
        float w = fmaxf(rx - lx, 0.0f), h = fmaxf(ry - ly, 0.0f);
        float I = w * h;
        float a2 = (cA.z - cA.x + 1.0f) * (cA.w - cA.y + 1.0f);
        bits |= (3.0f * I > a1 + a2) ? (1u << u) : 0u;   // iou>0.5 <=> 3I > a1+a2
    }
    adjG[(size_t)(b * N_ + r) * 64 + lane] = (unsigned short)bits;
}

// ---- K3 NEW: chunk-parallel sweep == R6's sequential sweep, reorganized ----
// Thread t = sorted position t. Wave c resolves chunk c (positions [64c,64c+64))
// serially in registers; later chunks apply kills in parallel. Pops monotone
// (R6-proven), so chunk order == pop order; output survG/KG identical to R6.
__global__ __launch_bounds__(1024) void sweep_kernel(
    const unsigned short* __restrict__ adjG, int* __restrict__ survG,
    int* __restrict__ KG) {
    const int b = blockIdx.x, t = threadIdx.x;
    const int wtop = t >> 6, lane = t & 63;
    __shared__ ull s_S[16];
    __shared__ int s_k;
    if (t == 0) s_k = 0;

    // my full adjacency row, one u64 per 64-position chunk (bit q = position 64c+q)
    const ull* rowp = (const ull*)(adjG + (size_t)(b * N_ + t) * 64);
    ull rw[16];
#pragma unroll
    for (int c = 0; c < 16; ++c) rw[c] = (c <= wtop) ? rowp[c] : 0ull;

    bool alive_f = true;
    __syncthreads();

#pragma unroll
    for (int c = 0; c < 16; ++c) {
        if (wtop == c) {   // wave-uniform condition; all 64 lanes active for ballot
            ull alive = __ballot(alive_f);
            ull Sc = 0ull;
            int k0 = s_k;   // wave-uniform (written by wave c-1 before last barrier)
            while (alive) {
                int p = (int)(__ffsll(alive) - 1);
                Sc |= 1ull << p;
                if (lane == 0) survG[b * N_ + k0] = c * 64 + p;
                k0++;
                // kills = row of position 64c+p restricted to this chunk (lane p's rw[c])
                unsigned klo = (unsigned)__builtin_amdgcn_readlane((int)(unsigned)rw[c], p);
                unsigned khi = (unsigned)__builtin_amdgcn_readlane((int)(unsigned)(rw[c] >> 32), p);
                ull kills = ((ull)khi << 32) | klo;
                alive &= ~kills;            // suppress neighbors (diag bit kills self)
                alive &= ~(1ull << p);      // belt-and-braces self clear
            }
            if (lane == 0) { s_S[c] = Sc; s_k = k0; }
        }
        __syncthreads();
        if (wtop > c && alive_f && (rw[c] & s_S[c]) != 0ull) alive_f = false;
    }
    __syncthreads();
    if (t == 0) KG[b] = s_k;
}

// ---- K4 (R6 verbatim): fully parallel loss from survivor list ----
__global__ __launch_bounds__(256) void loss_kernel(
    const float4* __restrict__ elemG, const unsigned short* __restrict__ adjG,
    const float* __restrict__ gt_bboxes, const int* __restrict__ survG,
    const int* __restrict__ KG, float* __restrict__ out) {
    const int b = blockIdx.x, t = threadIdx.x;
    __shared__ ull s_bits[16];               // survivor bitmask over sorted positions
    __shared__ unsigned short s_step[N_];    // position -> step (0xffff = suppressed)
    __shared__ float s_ts[N_];
    __shared__ int s_cnt[N_], s_kills[N_], s_first[G_];
    __shared__ float s_tpull, s_tpush;
    __shared__ int s_pcnt, s_qcnt;

    const int K = KG[b];
    const int* surv = survG + b * N_;
    for (int i = t; i < N_; i += 256) { s_step[i] = 0xffff; s_ts[i] = 0.f; s_cnt[i] = 0; s_kills[i] = 0; }
    if (t < 16) s_bits[t] = 0ull;
    if (t < G_) s_first[t] = 0x7fffffff;
    if (t == 0) { s_tpull = 0.f; s_tpush = 0.f; s_pcnt = 0; s_qcnt = 0; }
    __syncthreads();

    for (int k = t; k < K; k += 256) {
        int pos = surv[k];
        s_step[pos] = (unsigned short)k;
        atomicOr(&s_bits[pos >> 6], 1ull << (pos & 63));
        float4 eB = elemG[(size_t)(b * N_ + pos) * 2 + 1];
        atomicMin(&s_first[__float_as_int(eB.x)], k);   // first survivor of each gt
    }
    __syncthreads();

    // suppressed j: killer = first survivor q<j with adj(q,j) (symmetry: j's own row)
    for (int j = t; j < N_; j += 256) {
        if (s_step[j] != 0xffff) continue;
        const ull* rowp = (const ull*)(adjG + (size_t)(b * N_ + j) * 64);
        int kp = -1, wtop = j >> 6;
        for (int w = 0; w <= wtop; ++w) {
            ull m = rowp[w] & s_bits[w];
            if (w == wtop) m &= (j & 63) ? ((1ull << (j & 63)) - 1ull) : 0ull;
            if (m) { kp = w * 64 + (int)(__ffsll(m) - 1); break; }
        }
        if (kp < 0) continue;   // unreachable: every non-survivor has a killer
        int q = s_step[kp];
        atomicAdd(&s_kills[q], 1);   // 'remaining' evidence, pre-filter
        float4 qa = elemG[(size_t)(b * N_ + kp) * 2], qb = elemG[(size_t)(b * N_ + kp) * 2 + 1];
        float4 ja = elemG[(size_t)(b * N_ + j) * 2],  jb = elemG[(size_t)(b * N_ + j) * 2 + 1];
        int gq = __float_as_int(qb.x), gj = __float_as_int(jb.x);
        if (gq != gj) {
            float ov = iou1(qa.x, qa.y, qa.z, qa.w, ja.x, ja.y, ja.z, ja.w);
            const float* gbq = gt_bboxes + (size_t)(b * G_ + gq) * 4;
            const float* gbj = gt_bboxes + (size_t)(b * G_ + gj) * 4;
            float gov = iou1(gbq[0], gbq[1], gbq[2], gbq[3], gbj[0], gbj[1], gbj[2], gbj[3]);
            if (ov > gov) {
                atomicAdd(&s_cnt[q], 1);
                atomicAdd(&s_ts[q], -__logf(1.0f - ov) * jb.y);
            }
        }
    }
    __syncthreads();

    // pull per survivor + per-step push normalization
    for (int k = t; k < K; k += 256) {
        int pos = surv[k];
        float4 kB = elemG[(size_t)(b * N_ + pos) * 2 + 1];
        int g = __float_as_int(kB.x);
        int f = s_first[g];
        if (f < k) {
            atomicAdd(&s_pcnt, 1);   // NOT gated on remaining (matches reference)
            // step k's pull dropped iff it is the last pop and kills nobody (remaining=false)
            bool drop = (k == K - 1) && (s_kills[k] == 0);
            if (!drop) {
                int fpos = surv[f];
                float4 fA = elemG[(size_t)(b * N_ + fpos) * 2];
                float4 kA = elemG[(size_t)(b * N_ + pos) * 2];
                float ov = iou1(fA.x, fA.y, fA.z, fA.w, kA.x, kA.y, kA.z, kA.w);
                atomicAdd(&s_tpull, -__logf(0.5f + fmaxf(ov, 1e-6f)) * kB.y);
            }
        }
        if (s_cnt[k] > 0) {   // kills>0 => remaining true => always counted
            atomicAdd(&s_tpush, s_ts[k] / (float)s_cnt[k]);
            atomicAdd(&s_qcnt, s_cnt[k]);
        }
    }
    __syncthreads();
    if (t == 0) {
        atomicAdd(&out[0], (s_tpush / ((float)s_qcnt + 1e-6f)) * 0.125f);  // mean push, B=8
        atomicAdd(&out[1], (s_tpull / ((float)s_pcnt + 1e-6f)) * 0.125f);  // mean pull
    }
}

extern "C" void kernel_launch(void* const* d_in, const int* in_sizes, int n_in,
                              void* d_out, int out_size, void* d_ws, size_t ws_size,
                              hipStream_t stream) {
    const int* pos_inds = (const int*)d_in[0];
    const int* pos_gt = (const int*)d_in[1];
    const float* gt_bboxes = (const float*)d_in[2];
    const float* bbox_preds = (const float*)d_in[3];
    const float* cls_scores = (const float*)d_in[4];
    const int* gt_labels = (const int*)d_in[5];
    float* out = (float*)d_out;

    float4* elemG = (float4*)((char*)d_ws + WS_ELEM_OFF);
    unsigned short* adjG = (unsigned short*)((char*)d_ws + WS_ADJ_OFF);
    int* survG = (int*)((char*)d_ws + WS_SURV_OFF);
    int* KG = (int*)((char*)d_ws + WS_K_OFF);

    hipMemsetAsync(out, 0, 2 * sizeof(float), stream);  // d_out re-poisoned 0xAA each call
    prep_kernel<<<dim3(B_), dim3(1024), 0, stream>>>(
        pos_inds, pos_gt, bbox_preds, cls_scores, gt_labels, elemG);
    adj_kernel<<<dim3(256, B_), dim3(256), 0, stream>>>(elemG, adjG);
    sweep_kernel<<<dim3(B_), dim3(1024), 0, stream>>>(adjG, survG, KG);
    loss_kernel<<<dim3(B_), dim3(256), 0, stream>>>(elemG, adjG, gt_bboxes, survG, KG, out);
}

// Round 9
// 138.597 us; speedup vs baseline: 4.0651x; 1.5194x over previous
//
#include <hip/hip_runtime.h>
#include <math.h>

#define B_ 8
#define N_ 1024
#define M_ 20000
#define C_ 80
#define G_ 64
typedef unsigned long long ull;

// ws: elem [B][1024][2]float4 (256KB) | adj [B][1024][64]u16 (1MB)
#define WS_ELEM_OFF 0
#define WS_ADJ_OFF  262144

__device__ __forceinline__ float iou1(float ax, float ay, float az, float aw,
                                      float bx, float by, float bz, float bw) {
    // legacy +1 convention, exact reference arithmetic order
    float lx = fmaxf(ax, bx), ly = fmaxf(ay, by);
    float rx = fminf(az, bz), ry = fminf(aw, bw);
    float w = fmaxf(rx - lx + 1.0f, 0.0f), h = fmaxf(ry - ly + 1.0f, 0.0f);
    float ov = w * h;
    float a1 = (az - ax + 1.0f) * (aw - ay + 1.0f);
    float a2 = (bz - bx + 1.0f) * (bw - by + 1.0f);
    return ov / (a1 + a2 - ov);
}

// ---- K1 (R8 verbatim): scores + hybrid bitonic sort + sorted element table ----
__global__ __launch_bounds__(1024) void prep_kernel(
    const int* __restrict__ pos_inds, const int* __restrict__ pos_gt,
    const float* __restrict__ bbox_preds, const float* __restrict__ cls_scores,
    const int* __restrict__ gt_labels, float4* __restrict__ elemG) {
    const int b = blockIdx.x, t = threadIdx.x;
    __shared__ ull s_keys[N_];

    int g0 = pos_gt[b * N_ + t];
    int lab = gt_labels[b * G_ + g0];
    int pi = pos_inds[b * N_ + t];
    float s = cls_scores[(size_t)b * (M_ * C_) + (size_t)pi * C_ + lab];
    // descending score, tie -> ascending original index (jnp.argmax tie-break)
    ull key = ((ull)(~__float_as_uint(s)) << 32) | (unsigned)t;

    for (unsigned k2 = 2; k2 <= N_; k2 <<= 1) {
        for (unsigned jj = k2 >> 1; jj; jj >>= 1) {
            ull other;
            if (jj >= 64) {
                s_keys[t] = key; __syncthreads();
                other = s_keys[t ^ jj]; __syncthreads();
            } else {
                int lo = __shfl_xor((int)(unsigned)key, (int)jj);
                int hi = __shfl_xor((int)(unsigned)(key >> 32), (int)jj);
                other = ((ull)(unsigned)hi << 32) | (unsigned)lo;
            }
            bool keep_min = (((t & jj) == 0) == ((t & k2) == 0));
            ull mn = key < other ? key : other;
            ull mx = key < other ? other : key;
            key = keep_min ? mn : mx;
        }
    }

    int j = (int)(unsigned)(key & 0xFFFFFFFFull);
    float ss = __uint_as_float(~(unsigned)(key >> 32));   // exact score recovery
    const float* bp = bbox_preds + (size_t)(b * N_ + j) * 4;
    float x0 = bp[0], y0 = bp[1], x1 = bp[2], y1 = bp[3];
    int g = pos_gt[b * N_ + j];
    float area = (x1 - x0 + 1.0f) * (y1 - y0 + 1.0f);
    elemG[(size_t)(b * N_ + t) * 2 + 0] = make_float4(x0, y0, x1, y1);
    elemG[(size_t)(b * N_ + t) * 2 + 1] = make_float4(__int_as_float(g), ss, area, 0.f);
}

// ---- K2 (R8 verbatim): adjacency bits: bit q of row r = (iou(r,q) > 0.5) ----
__global__ __launch_bounds__(256) void adj_kernel(
    const float4* __restrict__ elemG, unsigned short* __restrict__ adjG) {
    const int b = blockIdx.y;
    const int r = blockIdx.x * 4 + (threadIdx.x >> 6);
    const int lane = threadIdx.x & 63;
    float4 rA = elemG[(size_t)(b * N_ + r) * 2];
    float ax0 = rA.x, ay0 = rA.y;
    float az1 = rA.z + 1.0f, aw1 = rA.w + 1.0f;
    float a1 = (rA.z - rA.x + 1.0f) * (rA.w - rA.y + 1.0f);
    unsigned bits = 0;
#pragma unroll
    for (int u = 0; u < 16; ++u) {
        int cpos = lane * 16 + u;
        float4 cA = elemG[(size_t)(b * N_ + cpos) * 2];
        float lx = fmaxf(ax0, cA.x), ly = fmaxf(ay0, cA.y);
        float rx = fminf(az1, cA.z + 1.0f), ry = fminf(aw1, cA.w + 1.0f);
        float w = fmaxf(rx - lx, 0.0f), h = fmaxf(ry - ly, 0.0f);
        float I = w * h;
        float a2 = (cA.z - cA.x + 1.0f) * (cA.w - cA.y + 1.0f);
        bits |= (3.0f * I > a1 + a2) ? (1u << u) : 0u;   // iou>0.5 <=> 3I > a1+a2
    }
    adjG[(size_t)(b * N_ + r) * 64 + lane] = (unsigned short)bits;
}

// ---- K3: fused sweep (batched-round chunk acceptance) + loss ----
// Thread t == sorted position t. Chunk c survivors: repeat {accept U = alive
// with no earlier-alive in-chunk neighbor; apply OR of U's kill rows} --
// provably identical to the serial greedy pop order (pops monotone, R6/R8).
__global__ __launch_bounds__(1024) void sweep_loss_kernel(
    const float4* __restrict__ elemG, const unsigned short* __restrict__ adjG,
    const float* __restrict__ gt_bboxes, float* __restrict__ out) {
    const int b = blockIdx.x, t = threadIdx.x;
    const int wtop = t >> 6, lane = t & 63;

    __shared__ float4 s_box[N_];           // 16 KB
    __shared__ float s_score[N_];          // 4 KB
    __shared__ short s_g[N_];              // 2 KB
    __shared__ ull s_S[16];                // survivor bitmask
    __shared__ unsigned short s_step[N_];  // position -> rank
    __shared__ unsigned short s_surv[N_];  // rank -> position
    __shared__ float s_ts[N_];             // per-step push sums
    __shared__ int s_cnt[N_], s_kills[N_], s_first[G_];
    __shared__ int s_wpre[17];
    __shared__ float s_tpull, s_tpush;
    __shared__ int s_pcnt, s_qcnt;

    {   // stage elements + init
        float4 eA = elemG[(size_t)(b * N_ + t) * 2];
        float4 eB = elemG[(size_t)(b * N_ + t) * 2 + 1];
        s_box[t] = eA; s_score[t] = eB.y; s_g[t] = (short)__float_as_int(eB.x);
    }
    s_ts[t] = 0.f; s_cnt[t] = 0; s_kills[t] = 0; s_step[t] = 0xffff;
    if (t < 16) s_S[t] = 0ull;
    if (t < G_) s_first[t] = 0x7fffffff;
    if (t == 0) { s_tpull = 0.f; s_tpush = 0.f; s_pcnt = 0; s_qcnt = 0; }

    // my adjacency row words for chunks <= mine (bit q of word c = adj(t, 64c+q))
    const ull* rowp = (const ull*)(adjG + (size_t)(b * N_ + t) * 64);
    ull rw[16];
#pragma unroll
    for (int c = 0; c < 16; ++c) rw[c] = (c <= wtop) ? rowp[c] : 0ull;

    __syncthreads();

    // ---- sweep: 16 ordered chunk phases ----
    bool alive_f = true;
#pragma unroll
    for (int c = 0; c < 16; ++c) {
        if (wtop == c) {   // wave-uniform; whole wave active
            ull alive = __ballot(alive_f);
            ull Sc = 0ull;
            const ull below = (1ull << lane) - 1ull;     // lane 0 -> 0
            const ull myearly = rw[c] & below;           // earlier in-chunk neighbors
            while (alive) {
                bool inU = ((alive >> lane) & 1ull) && ((myearly & alive) == 0ull);
                ull U = __ballot(inU);
                unsigned klo = inU ? (unsigned)rw[c] : 0u;
                unsigned khi = inU ? (unsigned)(rw[c] >> 32) : 0u;
#pragma unroll
                for (int off = 32; off; off >>= 1) {   // OR-reduce kill rows of U
                    klo |= (unsigned)__shfl_xor((int)klo, off);
                    khi |= (unsigned)__shfl_xor((int)khi, off);
                }
                ull kills = ((ull)khi << 32) | klo;
                Sc |= U;
                alive &= ~U;
                alive &= ~kills;
            }
            if (lane == 0) s_S[c] = Sc;
        }
        __syncthreads();
        if (wtop > c && alive_f && (rw[c] & s_S[c]) != 0ull) alive_f = false;
    }

    // ---- survivor ranks (pop order = ascending position, proven monotone) ----
    if (t < 16) s_wpre[t + 1] = __popcll(s_S[t]);
    __syncthreads();
    if (t == 0) { s_wpre[0] = 0; for (int w = 0; w < 16; ++w) s_wpre[w + 1] += s_wpre[w]; }
    __syncthreads();
    const int K = s_wpre[16];
    const ull sbit = 1ull << lane;
    const bool isS = (s_S[wtop] & sbit) != 0ull;
    int myrank = -1;
    if (isS) {
        myrank = s_wpre[wtop] + __popcll(s_S[wtop] & (sbit - 1ull));
        s_step[t] = (unsigned short)myrank;
        s_surv[myrank] = (unsigned short)t;
        atomicMin(&s_first[(int)s_g[t]], myrank);
    }
    __syncthreads();

    // ---- suppressed j: killer = first adjacent survivor below j ----
    if (!isS) {
        int kp = -1;
#pragma unroll
        for (int w = 15; w >= 0; --w) {   // descending so final = lowest word hit
            ull m = rw[w] & s_S[w];       // rw[w]=0 for w>wtop
            if (w == wtop) m &= (1ull << lane) - 1ull;
            if (m) kp = (w << 6) + (int)(__ffsll(m) - 1);
        }
        if (kp >= 0) {   // always true: every non-survivor has a killer
            int q = s_step[kp];
            atomicAdd(&s_kills[q], 1);   // 'remaining' evidence
            int gq = (int)s_g[kp], gj = (int)s_g[t];
            if (gq != gj) {
                float4 qa = s_box[kp], ja = s_box[t];
                float ov = iou1(qa.x, qa.y, qa.z, qa.w, ja.x, ja.y, ja.z, ja.w);
                const float* gbq = gt_bboxes + (size_t)(b * G_ + gq) * 4;
                const float* gbj = gt_bboxes + (size_t)(b * G_ + gj) * 4;
                float gov = iou1(gbq[0], gbq[1], gbq[2], gbq[3],
                                 gbj[0], gbj[1], gbj[2], gbj[3]);
                if (ov > gov) {
                    atomicAdd(&s_cnt[q], 1);
                    atomicAdd(&s_ts[q], -__logf(1.0f - ov) * s_score[t]);
                }
            }
        }
    }
    __syncthreads();

    // ---- pull per survivor + per-step push normalization ----
    if (isS) {
        int k = myrank, g = (int)s_g[t], f = s_first[g];
        if (f < k) {
            atomicAdd(&s_pcnt, 1);   // NOT gated on remaining (matches reference)
            // pull dropped iff last pop and it kills nobody (remaining == false)
            bool drop = (k == K - 1) && (s_kills[k] == 0);
            if (!drop) {
                float4 fA = s_box[s_surv[f]], kA = s_box[t];
                float ov = iou1(fA.x, fA.y, fA.z, fA.w, kA.x, kA.y, kA.z, kA.w);
                atomicAdd(&s_tpull, -__logf(0.5f + fmaxf(ov, 1e-6f)) * s_score[t]);
            }
        }
        if (s_cnt[k] > 0) {   // cnt>0 => kills>0 => remaining true
            atomicAdd(&s_tpush, s_ts[k] / (float)s_cnt[k]);
            atomicAdd(&s_qcnt, s_cnt[k]);
        }
    }
    __syncthreads();

    if (t == 0) {
        atomicAdd(&out[0], (s_tpush / ((float)s_qcnt + 1e-6f)) * 0.125f);  // mean push, B=8
        atomicAdd(&out[1], (s_tpull / ((float)s_pcnt + 1e-6f)) * 0.125f);  // mean pull
    }
}

extern "C" void kernel_launch(void* const* d_in, const int* in_sizes, int n_in,
                              void* d_out, int out_size, void* d_ws, size_t ws_size,
                              hipStream_t stream) {
    const int* pos_inds = (const int*)d_in[0];
    const int* pos_gt = (const int*)d_in[1];
    const float* gt_bboxes = (const float*)d_in[2];
    const float* bbox_preds = (const float*)d_in[3];
    const float* cls_scores = (const float*)d_in[4];
    const int* gt_labels = (const int*)d_in[5];
    float* out = (float*)d_out;

    float4* elemG = (float4*)((char*)d_ws + WS_ELEM_OFF);
    unsigned short* adjG = (unsigned short*)((char*)d_ws + WS_ADJ_OFF);

    hipMemsetAsync(out, 0, 2 * sizeof(float), stream);  // d_out re-poisoned 0xAA each call
    prep_kernel<<<dim3(B_), dim3(1024), 0, stream>>>(
        pos_inds, pos_gt, bbox_preds, cls_scores, gt_labels, elemG);
    adj_kernel<<<dim3(256, B_), dim3(256), 0, stream>>>(elemG, adjG);
    sweep_loss_kernel<<<dim3(B_), dim3(1024), 0, stream>>>(elemG, adjG, gt_bboxes, out);
}